// Round 4
// baseline (179.053 us; speedup 1.0000x reference)
//
#include <hip/hip_runtime.h>
#include <math.h>

// ---- problem constants ----
#define HH 32
#define WW 32
#define CC 128
#define PPIX 13
#define RPIX 6
#define NPIX 169      // 13*13
#define G14 14
#define NG 196        // 14*14
#define NTOT 338      // 2*169
#define DIRATE_ 2
#define HS 16
#define WSz 16
#define CS 512
#define PREG 7
#define RREG 3
#define NREG 49
#define QH 128        // quantized spatial dim
#define MAIN_BLOCKS 2048   // 2*32*32 pixels
#define REG_BLOCKS 512     // 2*16*16 semantic pixels

__device__ __forceinline__ float wave_sum(float v) {
    #pragma unroll
    for (int s = 1; s < 64; s <<= 1) v += __shfl_xor(v, s, 64);
    return v;
}
__device__ __forceinline__ float wave_max(float v) {
    #pragma unroll
    for (int s = 1; s < 64; s <<= 1) v = fmaxf(v, __shfl_xor(v, s, 64));
    return v;
}

// One prep kernel: 5 channels-last transposes + 2 quantized ::4 compactions.
// blocks 0..767    : feats {r0,r1,t}  [2][128][1024] -> [2][1024][128]
// blocks 768..1279 : semantic {rs1,ts} [2][512][256] -> [2][256][512]
// blocks 1280..1287: qs{0,1}[b][ch][y][x] = q{0,1}[b][ch][4y][4x]
__global__ __launch_bounds__(256) void prep(
    const float* __restrict__ fr0, const float* __restrict__ fr1,
    const float* __restrict__ ft,  const float* __restrict__ qr0,
    const float* __restrict__ qr1, const float* __restrict__ rs1,
    const float* __restrict__ ts,
    float* __restrict__ Tr0, float* __restrict__ Tr1, float* __restrict__ Tt,
    float* __restrict__ Trs1, float* __restrict__ Tts,
    float* __restrict__ qs0, float* __restrict__ qs1)
{
    __shared__ float tile[32][33];
    const int tid = threadIdx.x;
    const int tx = tid & 31, ty = tid >> 5;   // logical (32,8)
    int bid = blockIdx.x;
    if (bid < 768) {
        const int t = bid >> 8, rem = bid & 255;
        const int p0 = (rem & 31) * 32;        // 32 p-tiles (P=1024)
        const int c0 = ((rem >> 5) & 3) * 32;  // 4 c-tiles  (C=128)
        const int b  = rem >> 7;
        const float* s = (t==0 ? fr0 : t==1 ? fr1 : ft) + (size_t)b*CC*1024;
        float* d       = (t==0 ? Tr0 : t==1 ? Tr1 : Tt) + (size_t)b*CC*1024;
        #pragma unroll
        for (int i = ty; i < 32; i += 8) tile[i][tx] = s[(size_t)(c0+i)*1024 + p0+tx];
        __syncthreads();
        #pragma unroll
        for (int i = ty; i < 32; i += 8) d[(size_t)(p0+i)*CC + c0+tx] = tile[tx][i];
    } else if (bid < 1280) {
        bid -= 768;
        const int t = bid >> 8, rem = bid & 255;
        const int p0 = (rem & 7) * 32;          // 8 p-tiles (P=256)
        const int c0 = ((rem >> 3) & 15) * 32;  // 16 c-tiles (C=512)
        const int b  = rem >> 7;
        const float* s = (t==0 ? rs1 : ts) + (size_t)b*CS*256;
        float* d       = (t==0 ? Trs1 : Tts) + (size_t)b*CS*256;
        #pragma unroll
        for (int i = ty; i < 32; i += 8) tile[i][tx] = s[(size_t)(c0+i)*256 + p0+tx];
        __syncthreads();
        #pragma unroll
        for (int i = ty; i < 32; i += 8) d[(size_t)(p0+i)*CS + c0+tx] = tile[tx][i];
    } else {
        const int base = (bid - 1280) * 256 + tid;   // 0..2047
        for (int e = base; e < 2*6144; e += 2048) {
            const int t = e / 6144, r2 = e % 6144;   // r2 = (b*3+ch)*1024 + y*32 + x
            const int bc = r2 >> 10, yx = r2 & 1023;
            const int yy = yx >> 5, xx = yx & 31;
            const float v = (t==0 ? qr0 : qr1)[((size_t)bc*QH + yy*4)*QH + xx*4];
            (t==0 ? qs0 : qs1)[r2] = v;
        }
    }
}

__global__ __launch_bounds__(256) void colorizer_fused(
    const float* __restrict__ Tr0,   // [2][1024][128] channels-last
    const float* __restrict__ Tr1,
    const float* __restrict__ Tt,
    const float* __restrict__ qs0,   // [2][3][32][32] compact ::4 slice
    const float* __restrict__ qs1,
    const float* __restrict__ Trs1,  // [2][256][512]
    const float* __restrict__ Tts,
    float* __restrict__ out,         // [2,3,32,32]
    float* __restrict__ corr_out)    // [2,1,49,256]
{
    __shared__ __align__(16) float tvec[CS];  // main: 128, region: 512
    __shared__ float rbuf[40];                // disjoint reduction slots
    __shared__ float smG[NG];                 // region reuses for 49 dots
    __shared__ float smC1[NPIX];
    __shared__ float smV[NTOT];
    __shared__ float smQ0[3*NG];
    __shared__ float smQ1[3*NPIX];

    const int tid  = threadIdx.x;
    const int lane = tid & 63;
    const int wid  = tid >> 6;

    if (blockIdx.x < MAIN_BLOCKS) {
        const int b   = blockIdx.x >> 10;
        const int pix = blockIdx.x & 1023;
        const int y = pix >> 5, x = pix & 31;

        // stage t-vector (contiguous, channels-last)
        if (tid < 32)
            ((float4*)tvec)[tid] = ((const float4*)(Tt + ((size_t)b*1024 + pix)*CC))[tid];
        __syncthreads();

        // ---- coarse correlation (dilation 2), one dot per thread ----
        float dv = 0.f;
        if (tid < NPIX) {
            const int i = tid / PPIX, j = tid % PPIX;
            const int ys = y + (i - RPIX)*DIRATE_;
            const int xs = x + (j - RPIX)*DIRATE_;
            if (ys >= 0 && ys < HH && xs >= 0 && xs < WW) {
                const float4* rp = (const float4*)(Tr0 + ((size_t)b*1024 + ys*WW + xs)*CC);
                const float4* tp = (const float4*)tvec;
                float a0=0.f,a1=0.f,a2=0.f,a3=0.f;
                #pragma unroll
                for (int k = 0; k < CC/4; ++k) {
                    float4 rv = rp[k], tv = tp[k];
                    a0 = fmaf(rv.x, tv.x, a0); a1 = fmaf(rv.y, tv.y, a1);
                    a2 = fmaf(rv.z, tv.z, a2); a3 = fmaf(rv.w, tv.w, a3);
                }
                dv = (a0+a1)+(a2+a3);
            }
        }
        // softmax over 169 -> expected offset (wave reduce + 4-slot combine)
        {
            float wm = wave_max(tid < NPIX ? dv : -INFINITY);
            if (lane == 0) rbuf[wid] = wm;
        }
        __syncthreads();
        const float M1 = fmaxf(fmaxf(rbuf[0], rbuf[1]), fmaxf(rbuf[2], rbuf[3]));
        {
            const float e   = (tid < NPIX) ? __expf(dv - M1) : 0.f;
            const float gvj = (tid < NPIX) ? (float)(tid % PPIX - RPIX) : 0.f;
            const float gvi = (tid < NPIX) ? (float)(tid / PPIX - RPIX) : 0.f;
            float s0 = wave_sum(e), s1 = wave_sum(e*gvj), s2 = wave_sum(e*gvi);
            if (lane == 0) { rbuf[4+wid] = s0; rbuf[8+wid] = s1; rbuf[12+wid] = s2; }
        }
        __syncthreads();
        const float ssum = rbuf[4]+rbuf[5]+rbuf[6]+rbuf[7];
        const float sx   = rbuf[8]+rbuf[9]+rbuf[10]+rbuf[11];
        const float sy   = rbuf[12]+rbuf[13]+rbuf[14]+rbuf[15];
        const float off_x = sx / ssum * (float)DIRATE_;
        const float off_y = sy / ssum * (float)DIRATE_;

        const float fy = (float)y + off_y, fx = (float)x + off_x;
        const float fly = floorf(fy), flx = floorf(fx);
        const int yb = (int)fly - RPIX, xb = (int)flx - RPIX;
        const float wy = fy - fly, wx = fx - flx;
        const float w00 = (1.f-wy)*(1.f-wx), w01 = (1.f-wy)*wx;
        const float w10 = wy*(1.f-wx),       w11 = wy*wx;

        // ---- 365 dots: 14x14 integer grid on r0 + 13x13 corr1 on r1 ----
        for (int idx = tid; idx < NG + NPIX; idx += 256) {
            int ys, xs; const float* base; float* dst;
            if (idx < NG) {
                ys = yb + idx / G14; xs = xb + idx % G14;
                base = Tr0; dst = &smG[idx];
            } else {
                const int k = idx - NG;
                ys = y + k / PPIX - RPIX; xs = x + k % PPIX - RPIX;
                base = Tr1; dst = &smC1[k];
            }
            float a = 0.f;
            if (ys >= 0 && ys < HH && xs >= 0 && xs < WW) {
                const float4* rp = (const float4*)(base + ((size_t)b*1024 + ys*WW + xs)*CC);
                const float4* tp = (const float4*)tvec;
                float a0=0.f,a1=0.f,a2=0.f,a3=0.f;
                #pragma unroll
                for (int k2 = 0; k2 < CC/4; ++k2) {
                    float4 rv = rp[k2], tv = tp[k2];
                    a0 = fmaf(rv.x, tv.x, a0); a1 = fmaf(rv.y, tv.y, a1);
                    a2 = fmaf(rv.z, tv.z, a2); a3 = fmaf(rv.w, tv.w, a3);
                }
                a = (a0+a1)+(a2+a3);
            }
            *dst = a;
        }
        // stage qr0 (14x14 grid) and qr1 (13x13), 3 ch, from compact slices
        for (int idx = tid; idx < 3*NG; idx += 256) {
            const int ch = idx / NG, a2 = idx % NG;
            const int ys = yb + a2 / G14, xs = xb + a2 % G14;
            smQ0[idx] = (ys>=0 && ys<HH && xs>=0 && xs<WW)
                        ? qs0[(b*3+ch)*1024 + ys*WW + xs] : 0.f;
        }
        for (int idx = tid; idx < 3*NPIX; idx += 256) {
            const int ch = idx / NPIX, a2 = idx % NPIX;
            const int ys = y + a2 / PPIX - RPIX, xs = x + a2 % PPIX - RPIX;
            smQ1[idx] = (ys>=0 && ys<HH && xs>=0 && xs<WW)
                        ? qs1[(b*3+ch)*1024 + ys*WW + xs] : 0.f;
        }
        __syncthreads();

        // ---- logits = concat(bilinear(G), corr1) ----
        for (int idx = tid; idx < NTOT; idx += 256) {
            float v;
            if (idx < NPIX) {
                const int i = idx / PPIX, j = idx % PPIX;
                const int g = i*G14 + j;
                v = w00*smG[g] + w01*smG[g+1] + w10*smG[g+G14] + w11*smG[g+G14+1];
            } else {
                v = smC1[idx - NPIX];
            }
            smV[idx] = v;
        }
        __syncthreads();

        // ---- fused softmax + (corr_pixel * image_uf).sum(n) ----
        float ml = -INFINITY;
        for (int idx = tid; idx < NTOT; idx += 256) ml = fmaxf(ml, smV[idx]);
        {
            float wm = wave_max(ml);
            if (lane == 0) rbuf[16+wid] = wm;
        }
        __syncthreads();
        const float M2 = fmaxf(fmaxf(rbuf[16], rbuf[17]), fmaxf(rbuf[18], rbuf[19]));

        float dpart = 0.f, o0 = 0.f, o1 = 0.f, o2 = 0.f;
        for (int idx = tid; idx < NTOT; idx += 256) {
            const float ee = __expf(smV[idx] - M2);
            dpart += ee;
            if (idx < NPIX) {
                const int i = idx / PPIX, j = idx % PPIX;
                const int g = i*G14 + j;
                o0 += ee * (w00*smQ0[g]          + w01*smQ0[g+1]
                          + w10*smQ0[g+G14]      + w11*smQ0[g+G14+1]);
                o1 += ee * (w00*smQ0[NG+g]       + w01*smQ0[NG+g+1]
                          + w10*smQ0[NG+g+G14]   + w11*smQ0[NG+g+G14+1]);
                o2 += ee * (w00*smQ0[2*NG+g]     + w01*smQ0[2*NG+g+1]
                          + w10*smQ0[2*NG+g+G14] + w11*smQ0[2*NG+g+G14+1]);
            } else {
                const int k = idx - NPIX;
                o0 += ee * smQ1[k];
                o1 += ee * smQ1[NPIX + k];
                o2 += ee * smQ1[2*NPIX + k];
            }
        }
        {
            float s0 = wave_sum(dpart), s1 = wave_sum(o0), s2 = wave_sum(o1), s3 = wave_sum(o2);
            if (lane == 0) { rbuf[20+wid]=s0; rbuf[24+wid]=s1; rbuf[28+wid]=s2; rbuf[32+wid]=s3; }
        }
        __syncthreads();
        if (tid == 0) {
            const float denom = rbuf[20]+rbuf[21]+rbuf[22]+rbuf[23];
            const float inv = 1.f / denom;
            out[((b*3+0)*HH + y)*WW + x] = (rbuf[24]+rbuf[25]+rbuf[26]+rbuf[27]) * inv;
            out[((b*3+1)*HH + y)*WW + x] = (rbuf[28]+rbuf[29]+rbuf[30]+rbuf[31]) * inv;
            out[((b*3+2)*HH + y)*WW + x] = (rbuf[32]+rbuf[33]+rbuf[34]+rbuf[35]) * inv;
        }
    } else {
        // ---- region correlation on semantic feats + softmax ----
        const int rb  = blockIdx.x - MAIN_BLOCKS;
        const int b   = rb >> 8;
        const int pix = rb & 255;
        const int y = pix >> 4, x = pix & 15;

        // stage 512-ch t-vector (contiguous)
        if (tid < 128)
            ((float4*)tvec)[tid] = ((const float4*)(Tts + ((size_t)b*256 + pix)*CS))[tid];
        __syncthreads();

        // 49 dots x 512 ch, 4 lanes per dot (128 ch each, contiguous float4)
        const int d = tid >> 2, q = tid & 3;
        float part = 0.f;
        if (d < NREG) {
            const int ys = y + d / PREG - RREG, xs = x + d % PREG - RREG;
            if (ys >= 0 && ys < HS && xs >= 0 && xs < WSz) {
                const float4* rp = (const float4*)(Trs1 + ((size_t)b*256 + ys*WSz + xs)*CS) + q*32;
                const float4* tp = (const float4*)tvec + q*32;
                float a0=0.f,a1=0.f,a2=0.f,a3=0.f;
                #pragma unroll
                for (int k = 0; k < 32; ++k) {
                    float4 rv = rp[k], tv = tp[k];
                    a0 = fmaf(rv.x, tv.x, a0); a1 = fmaf(rv.y, tv.y, a1);
                    a2 = fmaf(rv.z, tv.z, a2); a3 = fmaf(rv.w, tv.w, a3);
                }
                part = (a0+a1)+(a2+a3);
            }
        }
        // 4-lane reduce (aligned groups)
        part += __shfl_xor(part, 1, 64);
        part += __shfl_xor(part, 2, 64);
        if (q == 0 && d < NREG) smG[d] = part;
        __syncthreads();

        const bool act = tid < NREG;
        const float val = act ? smG[tid] : -INFINITY;
        {
            float wm = wave_max(val);
            if (lane == 0) rbuf[wid] = wm;
        }
        __syncthreads();
        const float M = fmaxf(fmaxf(rbuf[0], rbuf[1]), fmaxf(rbuf[2], rbuf[3]));
        const float e = act ? __expf(val - M) : 0.f;
        {
            float s0 = wave_sum(e);
            if (lane == 0) rbuf[4+wid] = s0;
        }
        __syncthreads();
        const float s = rbuf[4]+rbuf[5]+rbuf[6]+rbuf[7];
        if (act) corr_out[b*NREG*(HS*WSz) + tid*(HS*WSz) + pix] = e / s;
    }
}

extern "C" void kernel_launch(void* const* d_in, const int* in_sizes, int n_in,
                              void* d_out, int out_size, void* d_ws, size_t ws_size,
                              hipStream_t stream) {
    const float* feats_r0 = (const float*)d_in[0];
    const float* feats_r1 = (const float*)d_in[1];
    const float* feats_t  = (const float*)d_in[2];
    const float* q_r0     = (const float*)d_in[3];
    const float* q_r1     = (const float*)d_in[4];
    // d_in[5] = feats_r_semantic0 (unused by reference)
    const float* rs1      = (const float*)d_in[6];
    const float* ts       = (const float*)d_in[7];

    float* ws = (float*)d_ws;
    float* Tr0  = ws;               // 2*1024*128 = 262144
    float* Tr1  = Tr0  + 262144;
    float* Tt   = Tr1  + 262144;
    float* Trs1 = Tt   + 262144;    // 2*256*512 = 262144
    float* Tts  = Trs1 + 262144;
    float* qs0  = Tts  + 262144;    // 2*3*32*32 = 6144
    float* qs1  = qs0  + 6144;

    prep<<<1288, 256, 0, stream>>>(feats_r0, feats_r1, feats_t, q_r0, q_r1,
                                   rs1, ts, Tr0, Tr1, Tt, Trs1, Tts, qs0, qs1);

    float* out  = (float*)d_out;                 // [2,3,32,32] = 6144 floats
    float* corr = out + 2*3*HH*WW;               // [2,1,49,256] = 25088 floats

    colorizer_fused<<<MAIN_BLOCKS + REG_BLOCKS, 256, 0, stream>>>(
        Tr0, Tr1, Tt, qs0, qs1, Trs1, Tts, out, corr);
}

// Round 5
// 102.010 us; speedup vs baseline: 1.7553x; 1.7553x over previous
//
#include <hip/hip_runtime.h>
#include <math.h>

// ---- problem constants ----
#define HH 32
#define WW 32
#define CC 128
#define PPIX 13
#define RPIX 6
#define NPIX 169      // 13*13
#define G14 14
#define NG 196        // 14*14
#define NTOT 338      // 2*169
#define DIRATE_ 2
#define HS 16
#define WSz 16
#define CS 512
#define PREG 7
#define RREG 3
#define NREG 49
#define QH 128        // quantized spatial dim
#define MAIN_BLOCKS 2048   // 2*32*32 pixels
#define REG_BLOCKS 512     // 2*16*16 semantic pixels

__device__ __forceinline__ float wave_sum(float v) {
    #pragma unroll
    for (int s = 1; s < 64; s <<= 1) v += __shfl_xor(v, s, 64);
    return v;
}
__device__ __forceinline__ float wave_max(float v) {
    #pragma unroll
    for (int s = 1; s < 64; s <<= 1) v = fmaxf(v, __shfl_xor(v, s, 64));
    return v;
}

// One prep kernel: 5 channels-last transposes + 2 quantized ::4 compactions.
__global__ __launch_bounds__(256) void prep(
    const float* __restrict__ fr0, const float* __restrict__ fr1,
    const float* __restrict__ ft,  const float* __restrict__ qr0,
    const float* __restrict__ qr1, const float* __restrict__ rs1,
    const float* __restrict__ ts,
    float* __restrict__ Tr0, float* __restrict__ Tr1, float* __restrict__ Tt,
    float* __restrict__ Trs1, float* __restrict__ Tts,
    float* __restrict__ qs0, float* __restrict__ qs1)
{
    __shared__ float tile[32][33];
    const int tid = threadIdx.x;
    const int tx = tid & 31, ty = tid >> 5;   // logical (32,8)
    int bid = blockIdx.x;
    if (bid < 768) {
        const int t = bid >> 8, rem = bid & 255;
        const int p0 = (rem & 31) * 32;        // 32 p-tiles (P=1024)
        const int c0 = ((rem >> 5) & 3) * 32;  // 4 c-tiles  (C=128)
        const int b  = rem >> 7;
        const float* s = (t==0 ? fr0 : t==1 ? fr1 : ft) + (size_t)b*CC*1024;
        float* d       = (t==0 ? Tr0 : t==1 ? Tr1 : Tt) + (size_t)b*CC*1024;
        #pragma unroll
        for (int i = ty; i < 32; i += 8) tile[i][tx] = s[(size_t)(c0+i)*1024 + p0+tx];
        __syncthreads();
        #pragma unroll
        for (int i = ty; i < 32; i += 8) d[(size_t)(p0+i)*CC + c0+tx] = tile[tx][i];
    } else if (bid < 1280) {
        bid -= 768;
        const int t = bid >> 8, rem = bid & 255;
        const int p0 = (rem & 7) * 32;          // 8 p-tiles (P=256)
        const int c0 = ((rem >> 3) & 15) * 32;  // 16 c-tiles (C=512)
        const int b  = rem >> 7;
        const float* s = (t==0 ? rs1 : ts) + (size_t)b*CS*256;
        float* d       = (t==0 ? Trs1 : Tts) + (size_t)b*CS*256;
        #pragma unroll
        for (int i = ty; i < 32; i += 8) tile[i][tx] = s[(size_t)(c0+i)*256 + p0+tx];
        __syncthreads();
        #pragma unroll
        for (int i = ty; i < 32; i += 8) d[(size_t)(p0+i)*CS + c0+tx] = tile[tx][i];
    } else {
        const int base = (bid - 1280) * 256 + tid;   // 0..2047
        for (int e = base; e < 2*6144; e += 2048) {
            const int t = e / 6144, r2 = e % 6144;   // r2 = (b*3+ch)*1024 + y*32 + x
            const int bc = r2 >> 10, yx = r2 & 1023;
            const int yy = yx >> 5, xx = yx & 31;
            const float v = (t==0 ? qr0 : qr1)[((size_t)bc*QH + yy*4)*QH + xx*4];
            (t==0 ? qs0 : qs1)[r2] = v;
        }
    }
}

__global__ __launch_bounds__(256) void colorizer_fused(
    const float* __restrict__ Tr0,   // [2][1024][128] channels-last
    const float* __restrict__ Tr1,
    const float* __restrict__ Tt,
    const float* __restrict__ qs0,   // [2][3][32][32] compact ::4 slice
    const float* __restrict__ qs1,
    const float* __restrict__ Trs1,  // [2][256][512]
    const float* __restrict__ Tts,
    float* __restrict__ out,         // [2,3,32,32]
    float* __restrict__ corr_out)    // [2,1,49,256]
{
    __shared__ __align__(16) float tvec[CS];  // main: 128, region: 512
    __shared__ float rbuf[40];                // disjoint reduction slots
    __shared__ float smC0[NPIX];              // coarse dots
    __shared__ float smG[NG];                 // region reuses for 49 dots
    __shared__ float smC1[NPIX];
    __shared__ float smV[NTOT];
    __shared__ float smQ0[3*NG];
    __shared__ float smQ1[3*NPIX];

    const int tid  = threadIdx.x;
    const int lane = tid & 63;
    const int wid  = tid >> 6;

    if (blockIdx.x < MAIN_BLOCKS) {
        const int b   = blockIdx.x >> 10;
        const int pix = blockIdx.x & 1023;
        const int y = pix >> 5, x = pix & 31;

        // stage t-vector (contiguous, channels-last)
        if (tid < 32)
            ((float4*)tvec)[tid] = ((const float4*)Tt)[(size_t)b*32768 + pix*32 + tid];
        __syncthreads();

        const float4* tp  = (const float4*)tvec;
        const float4* Tr0q = (const float4*)Tr0 + (size_t)b*32768;
        const float4* Tr1q = (const float4*)Tr1 + (size_t)b*32768;
        const int q4 = lane & 3, g4 = lane >> 2;   // 16 dot-groups per wave

        // ---- coarse corr (dilation 2): 169 dots, 4 lanes each, 8 rounds x 64B ----
        #pragma unroll
        for (int set = 0; set < 3; ++set) {
            const int di = set*64 + wid*16 + g4;
            int inb = 0, yx = 0;
            if (di < NPIX) {
                const int ys = y + (di/PPIX - RPIX)*DIRATE_;
                const int xs = x + (di%PPIX - RPIX)*DIRATE_;
                inb = (ys>=0 && ys<HH && xs>=0 && xs<WW);
                yx = inb ? ys*WW+xs : 0;
            }
            const float4* rp = Tr0q + yx*32 + q4;
            float4 a; a.x=a.y=a.z=a.w=0.f;
            #pragma unroll
            for (int r = 0; r < 8; ++r) {
                const float4 rv = rp[r*4];
                const float4 tv = tp[q4 + r*4];
                a.x = fmaf(rv.x,tv.x,a.x); a.y = fmaf(rv.y,tv.y,a.y);
                a.z = fmaf(rv.z,tv.z,a.z); a.w = fmaf(rv.w,tv.w,a.w);
            }
            float s = (a.x+a.y)+(a.z+a.w);
            s += __shfl_xor(s, 1, 64); s += __shfl_xor(s, 2, 64);
            if (q4 == 0 && di < NPIX) smC0[di] = inb ? s : 0.f;
        }
        __syncthreads();

        // softmax over 169 -> expected offset (wave reduce + 4-slot combine)
        const float dv = (tid < NPIX) ? smC0[tid] : 0.f;
        {
            float wm = wave_max(tid < NPIX ? dv : -INFINITY);
            if (lane == 0) rbuf[wid] = wm;
        }
        __syncthreads();
        const float M1 = fmaxf(fmaxf(rbuf[0], rbuf[1]), fmaxf(rbuf[2], rbuf[3]));
        {
            const float e   = (tid < NPIX) ? __expf(dv - M1) : 0.f;
            const float gvj = (tid < NPIX) ? (float)(tid % PPIX - RPIX) : 0.f;
            const float gvi = (tid < NPIX) ? (float)(tid / PPIX - RPIX) : 0.f;
            float s0 = wave_sum(e), s1 = wave_sum(e*gvj), s2 = wave_sum(e*gvi);
            if (lane == 0) { rbuf[4+wid] = s0; rbuf[8+wid] = s1; rbuf[12+wid] = s2; }
        }
        __syncthreads();
        const float ssum = rbuf[4]+rbuf[5]+rbuf[6]+rbuf[7];
        const float sx   = rbuf[8]+rbuf[9]+rbuf[10]+rbuf[11];
        const float sy   = rbuf[12]+rbuf[13]+rbuf[14]+rbuf[15];
        const float off_x = sx / ssum * (float)DIRATE_;
        const float off_y = sy / ssum * (float)DIRATE_;

        const float fy = (float)y + off_y, fx = (float)x + off_x;
        const float fly = floorf(fy), flx = floorf(fx);
        const int yb = (int)fly - RPIX, xb = (int)flx - RPIX;
        const float wy = fy - fly, wx = fx - flx;
        const float w00 = (1.f-wy)*(1.f-wx), w01 = (1.f-wy)*wx;
        const float w10 = wy*(1.f-wx),       w11 = wy*wx;

        // ---- 365 dots (196 G-grid on r0 + 169 corr1 on r1), 4 lanes each ----
        #pragma unroll
        for (int set = 0; set < 6; ++set) {
            const int di = set*64 + wid*16 + g4;
            const float4* basep = Tr0q;
            int inb = 0, yx = 0;
            if (di < NG) {
                const int ys = yb + di/G14, xs = xb + di%G14;
                inb = (ys>=0 && ys<HH && xs>=0 && xs<WW);
                yx = inb ? ys*WW+xs : 0;
            } else if (di < NG+NPIX) {
                const int k = di - NG;
                const int ys = y + k/PPIX - RPIX, xs = x + k%PPIX - RPIX;
                inb = (ys>=0 && ys<HH && xs>=0 && xs<WW);
                yx = inb ? ys*WW+xs : 0;
                basep = Tr1q;
            }
            const float4* rp = basep + yx*32 + q4;
            float4 a; a.x=a.y=a.z=a.w=0.f;
            #pragma unroll
            for (int r = 0; r < 8; ++r) {
                const float4 rv = rp[r*4];
                const float4 tv = tp[q4 + r*4];
                a.x = fmaf(rv.x,tv.x,a.x); a.y = fmaf(rv.y,tv.y,a.y);
                a.z = fmaf(rv.z,tv.z,a.z); a.w = fmaf(rv.w,tv.w,a.w);
            }
            float s = (a.x+a.y)+(a.z+a.w);
            s += __shfl_xor(s, 1, 64); s += __shfl_xor(s, 2, 64);
            if (q4 == 0 && di < NG+NPIX) {
                if (di < NG) smG[di] = inb ? s : 0.f;
                else         smC1[di-NG] = inb ? s : 0.f;
            }
        }
        // stage qr0 (14x14 grid) and qr1 (13x13), 3 ch, from compact slices
        for (int idx = tid; idx < 3*NG; idx += 256) {
            const int ch = idx / NG, a2 = idx % NG;
            const int ys = yb + a2 / G14, xs = xb + a2 % G14;
            smQ0[idx] = (ys>=0 && ys<HH && xs>=0 && xs<WW)
                        ? qs0[(b*3+ch)*1024 + ys*WW + xs] : 0.f;
        }
        for (int idx = tid; idx < 3*NPIX; idx += 256) {
            const int ch = idx / NPIX, a2 = idx % NPIX;
            const int ys = y + a2 / PPIX - RPIX, xs = x + a2 % PPIX - RPIX;
            smQ1[idx] = (ys>=0 && ys<HH && xs>=0 && xs<WW)
                        ? qs1[(b*3+ch)*1024 + ys*WW + xs] : 0.f;
        }
        __syncthreads();

        // ---- logits = concat(bilinear(G), corr1) ----
        for (int idx = tid; idx < NTOT; idx += 256) {
            float v;
            if (idx < NPIX) {
                const int i = idx / PPIX, j = idx % PPIX;
                const int g = i*G14 + j;
                v = w00*smG[g] + w01*smG[g+1] + w10*smG[g+G14] + w11*smG[g+G14+1];
            } else {
                v = smC1[idx - NPIX];
            }
            smV[idx] = v;
        }
        __syncthreads();

        // ---- fused softmax + (corr_pixel * image_uf).sum(n) ----
        float ml = -INFINITY;
        for (int idx = tid; idx < NTOT; idx += 256) ml = fmaxf(ml, smV[idx]);
        {
            float wm = wave_max(ml);
            if (lane == 0) rbuf[16+wid] = wm;
        }
        __syncthreads();
        const float M2 = fmaxf(fmaxf(rbuf[16], rbuf[17]), fmaxf(rbuf[18], rbuf[19]));

        float dpart = 0.f, o0 = 0.f, o1 = 0.f, o2 = 0.f;
        for (int idx = tid; idx < NTOT; idx += 256) {
            const float ee = __expf(smV[idx] - M2);
            dpart += ee;
            if (idx < NPIX) {
                const int i = idx / PPIX, j = idx % PPIX;
                const int g = i*G14 + j;
                o0 += ee * (w00*smQ0[g]          + w01*smQ0[g+1]
                          + w10*smQ0[g+G14]      + w11*smQ0[g+G14+1]);
                o1 += ee * (w00*smQ0[NG+g]       + w01*smQ0[NG+g+1]
                          + w10*smQ0[NG+g+G14]   + w11*smQ0[NG+g+G14+1]);
                o2 += ee * (w00*smQ0[2*NG+g]     + w01*smQ0[2*NG+g+1]
                          + w10*smQ0[2*NG+g+G14] + w11*smQ0[2*NG+g+G14+1]);
            } else {
                const int k = idx - NPIX;
                o0 += ee * smQ1[k];
                o1 += ee * smQ1[NPIX + k];
                o2 += ee * smQ1[2*NPIX + k];
            }
        }
        {
            float s0 = wave_sum(dpart), s1 = wave_sum(o0), s2 = wave_sum(o1), s3 = wave_sum(o2);
            if (lane == 0) { rbuf[20+wid]=s0; rbuf[24+wid]=s1; rbuf[28+wid]=s2; rbuf[32+wid]=s3; }
        }
        __syncthreads();
        if (tid == 0) {
            const float denom = rbuf[20]+rbuf[21]+rbuf[22]+rbuf[23];
            const float inv = 1.f / denom;
            out[((b*3+0)*HH + y)*WW + x] = (rbuf[24]+rbuf[25]+rbuf[26]+rbuf[27]) * inv;
            out[((b*3+1)*HH + y)*WW + x] = (rbuf[28]+rbuf[29]+rbuf[30]+rbuf[31]) * inv;
            out[((b*3+2)*HH + y)*WW + x] = (rbuf[32]+rbuf[33]+rbuf[34]+rbuf[35]) * inv;
        }
    } else {
        // ---- region correlation on semantic feats + softmax ----
        const int rb  = blockIdx.x - MAIN_BLOCKS;
        const int b   = rb >> 8;
        const int pix = rb & 255;
        const int y = pix >> 4, x = pix & 15;

        // stage 512-ch t-vector (contiguous)
        if (tid < 128)
            ((float4*)tvec)[tid] = ((const float4*)Tts)[(size_t)b*32768 + pix*128 + tid];
        __syncthreads();

        const float4* tp  = (const float4*)tvec;
        const float4* Tsq = (const float4*)Trs1 + (size_t)b*32768;
        const int q8 = lane & 7, g8 = lane >> 3;   // 8 dot-groups per wave

        // 49 dots x 512 ch, 8 lanes per dot, 16 rounds x 128B
        #pragma unroll
        for (int set = 0; set < 2; ++set) {
            const int di = set*32 + wid*8 + g8;
            int inb = 0, yx = 0;
            if (di < NREG) {
                const int ys = y + di/PREG - RREG, xs = x + di%PREG - RREG;
                inb = (ys>=0 && ys<HS && xs>=0 && xs<WSz);
                yx = inb ? ys*WSz+xs : 0;
            }
            const float4* rp = Tsq + yx*128 + q8;
            float4 a; a.x=a.y=a.z=a.w=0.f;
            #pragma unroll 8
            for (int r = 0; r < 16; ++r) {
                const float4 rv = rp[r*8];
                const float4 tv = tp[q8 + r*8];
                a.x = fmaf(rv.x,tv.x,a.x); a.y = fmaf(rv.y,tv.y,a.y);
                a.z = fmaf(rv.z,tv.z,a.z); a.w = fmaf(rv.w,tv.w,a.w);
            }
            float s = (a.x+a.y)+(a.z+a.w);
            s += __shfl_xor(s, 1, 64); s += __shfl_xor(s, 2, 64); s += __shfl_xor(s, 4, 64);
            if (q8 == 0 && di < NREG) smG[di] = inb ? s : 0.f;
        }
        __syncthreads();

        const bool act = tid < NREG;
        const float val = act ? smG[tid] : -INFINITY;
        {
            float wm = wave_max(val);
            if (lane == 0) rbuf[wid] = wm;
        }
        __syncthreads();
        const float M = fmaxf(fmaxf(rbuf[0], rbuf[1]), fmaxf(rbuf[2], rbuf[3]));
        const float e = act ? __expf(val - M) : 0.f;
        {
            float s0 = wave_sum(e);
            if (lane == 0) rbuf[4+wid] = s0;
        }
        __syncthreads();
        const float s = rbuf[4]+rbuf[5]+rbuf[6]+rbuf[7];
        if (act) corr_out[b*NREG*(HS*WSz) + tid*(HS*WSz) + pix] = e / s;
    }
}

extern "C" void kernel_launch(void* const* d_in, const int* in_sizes, int n_in,
                              void* d_out, int out_size, void* d_ws, size_t ws_size,
                              hipStream_t stream) {
    const float* feats_r0 = (const float*)d_in[0];
    const float* feats_r1 = (const float*)d_in[1];
    const float* feats_t  = (const float*)d_in[2];
    const float* q_r0     = (const float*)d_in[3];
    const float* q_r1     = (const float*)d_in[4];
    // d_in[5] = feats_r_semantic0 (unused by reference)
    const float* rs1      = (const float*)d_in[6];
    const float* ts       = (const float*)d_in[7];

    float* ws = (float*)d_ws;
    float* Tr0  = ws;               // 2*1024*128 = 262144
    float* Tr1  = Tr0  + 262144;
    float* Tt   = Tr1  + 262144;
    float* Trs1 = Tt   + 262144;    // 2*256*512 = 262144
    float* Tts  = Trs1 + 262144;
    float* qs0  = Tts  + 262144;    // 2*3*32*32 = 6144
    float* qs1  = qs0  + 6144;

    prep<<<1288, 256, 0, stream>>>(feats_r0, feats_r1, feats_t, q_r0, q_r1,
                                   rs1, ts, Tr0, Tr1, Tt, Trs1, Tts, qs0, qs1);

    float* out  = (float*)d_out;                 // [2,3,32,32] = 6144 floats
    float* corr = out + 2*3*HH*WW;               // [2,1,49,256] = 25088 floats

    colorizer_fused<<<MAIN_BLOCKS + REG_BLOCKS, 256, 0, stream>>>(
        Tr0, Tr1, Tt, qs0, qs1, Trs1, Tts, out, corr);
}

// Round 6
// 99.627 us; speedup vs baseline: 1.7972x; 1.0239x over previous
//
#include <hip/hip_runtime.h>
#include <math.h>

// ---- problem constants ----
#define HH 32
#define WW 32
#define CC 128
#define PPIX 13
#define RPIX 6
#define NPIX 169      // 13*13
#define G14 14
#define NG 196        // 14*14
#define NTOT 338      // 2*169
#define DIRATE_ 2
#define HS 16
#define WSz 16
#define CS 512
#define PREG 7
#define RREG 3
#define NREG 49
#define QH 128        // quantized spatial dim
#define MAIN_BLOCKS 2048   // 2*32*32 pixels
#define REG_BLOCKS 512     // 2*16*16 semantic pixels

__device__ __forceinline__ float wave_sum(float v) {
    #pragma unroll
    for (int s = 1; s < 64; s <<= 1) v += __shfl_xor(v, s, 64);
    return v;
}
__device__ __forceinline__ float wave_max(float v) {
    #pragma unroll
    for (int s = 1; s < 64; s <<= 1) v = fmaxf(v, __shfl_xor(v, s, 64));
    return v;
}

// One prep kernel: 5 channels-last transposes + 2 quantized ::4 compactions.
__global__ __launch_bounds__(256) void prep(
    const float* __restrict__ fr0, const float* __restrict__ fr1,
    const float* __restrict__ ft,  const float* __restrict__ qr0,
    const float* __restrict__ qr1, const float* __restrict__ rs1,
    const float* __restrict__ ts,
    float* __restrict__ Tr0, float* __restrict__ Tr1, float* __restrict__ Tt,
    float* __restrict__ Trs1, float* __restrict__ Tts,
    float* __restrict__ qs0, float* __restrict__ qs1)
{
    __shared__ float tile[32][33];
    const int tid = threadIdx.x;
    const int tx = tid & 31, ty = tid >> 5;   // logical (32,8)
    int bid = blockIdx.x;
    if (bid < 768) {
        const int t = bid >> 8, rem = bid & 255;
        const int p0 = (rem & 31) * 32;        // 32 p-tiles (P=1024)
        const int c0 = ((rem >> 5) & 3) * 32;  // 4 c-tiles  (C=128)
        const int b  = rem >> 7;
        const float* s = (t==0 ? fr0 : t==1 ? fr1 : ft) + (size_t)b*CC*1024;
        float* d       = (t==0 ? Tr0 : t==1 ? Tr1 : Tt) + (size_t)b*CC*1024;
        #pragma unroll
        for (int i = ty; i < 32; i += 8) tile[i][tx] = s[(size_t)(c0+i)*1024 + p0+tx];
        __syncthreads();
        #pragma unroll
        for (int i = ty; i < 32; i += 8) d[(size_t)(p0+i)*CC + c0+tx] = tile[tx][i];
    } else if (bid < 1280) {
        bid -= 768;
        const int t = bid >> 8, rem = bid & 255;
        const int p0 = (rem & 7) * 32;          // 8 p-tiles (P=256)
        const int c0 = ((rem >> 3) & 15) * 32;  // 16 c-tiles (C=512)
        const int b  = rem >> 7;
        const float* s = (t==0 ? rs1 : ts) + (size_t)b*CS*256;
        float* d       = (t==0 ? Trs1 : Tts) + (size_t)b*CS*256;
        #pragma unroll
        for (int i = ty; i < 32; i += 8) tile[i][tx] = s[(size_t)(c0+i)*256 + p0+tx];
        __syncthreads();
        #pragma unroll
        for (int i = ty; i < 32; i += 8) d[(size_t)(p0+i)*CS + c0+tx] = tile[tx][i];
    } else {
        const int base = (bid - 1280) * 256 + tid;   // 0..2047
        for (int e = base; e < 2*6144; e += 2048) {
            const int t = e / 6144, r2 = e % 6144;   // r2 = (b*3+ch)*1024 + y*32 + x
            const int bc = r2 >> 10, yx = r2 & 1023;
            const int yy = yx >> 5, xx = yx & 31;
            const float v = (t==0 ? qr0 : qr1)[((size_t)bc*QH + yy*4)*QH + xx*4];
            (t==0 ? qs0 : qs1)[r2] = v;
        }
    }
}

__global__ __launch_bounds__(256) void colorizer_fused(
    const float* __restrict__ Tr0,   // [2][1024][128] channels-last
    const float* __restrict__ Tr1,
    const float* __restrict__ Tt,
    const float* __restrict__ qs0,   // [2][3][32][32] compact ::4 slice
    const float* __restrict__ qs1,
    const float* __restrict__ Trs1,  // [2][256][512]
    const float* __restrict__ Tts,
    float* __restrict__ out,         // [2,3,32,32]
    float* __restrict__ corr_out)    // [2,1,49,256]
{
    __shared__ __align__(16) float tvec[CS];  // main: 128, region: 512
    __shared__ float rbuf[40];                // disjoint reduction slots
    __shared__ float smC0[NPIX];              // coarse dots
    __shared__ float smG[NG];                 // region reuses for 49 dots
    __shared__ float smC1[NPIX];
    __shared__ float smV[NTOT];
    __shared__ float smQ0[3*NG];
    __shared__ float smQ1[3*NPIX];

    const int tid  = threadIdx.x;
    const int lane = tid & 63;
    const int wid  = tid >> 6;

    if (blockIdx.x < MAIN_BLOCKS) {
        // XCD-aware chunked swizzle: each XCD gets a contiguous pixel range
        const int bid = (blockIdx.x & 7) * (MAIN_BLOCKS/8) + (blockIdx.x >> 3);
        const int b   = bid >> 10;
        const int pix = bid & 1023;
        const int y = pix >> 5, x = pix & 31;

        // stage t-vector (contiguous, channels-last)
        if (tid < 32)
            ((float4*)tvec)[tid] = ((const float4*)Tt)[(size_t)b*32768 + pix*32 + tid];
        __syncthreads();

        const float4* tp  = (const float4*)tvec;
        const float4* Tr0q = (const float4*)Tr0 + (size_t)b*32768;
        const float4* Tr1q = (const float4*)Tr1 + (size_t)b*32768;
        const int q4 = lane & 3, g4 = lane >> 2;   // 16 dot-groups per wave

        // hoist this lane's t-fragment (8 float4 = 32 ch) into registers
        float4 tf[8];
        #pragma unroll
        for (int r = 0; r < 8; ++r) tf[r] = tp[q4 + r*4];

        // ---- coarse corr (dilation 2): 169 dots, 4 lanes each ----
        #pragma unroll 1
        for (int set = 0; set < 3; ++set) {
            const int di = set*64 + wid*16 + g4;
            int inb = 0, yx = 0;
            if (di < NPIX) {
                const int ys = y + (di/PPIX - RPIX)*DIRATE_;
                const int xs = x + (di%PPIX - RPIX)*DIRATE_;
                inb = (ys>=0 && ys<HH && xs>=0 && xs<WW);
                yx = inb ? ys*WW+xs : 0;
            }
            const float4* rp = Tr0q + yx*32 + q4;
            float4 a; a.x=a.y=a.z=a.w=0.f;
            #pragma unroll
            for (int r = 0; r < 8; ++r) {
                const float4 rv = rp[r*4];
                a.x = fmaf(rv.x,tf[r].x,a.x); a.y = fmaf(rv.y,tf[r].y,a.y);
                a.z = fmaf(rv.z,tf[r].z,a.z); a.w = fmaf(rv.w,tf[r].w,a.w);
            }
            float s = (a.x+a.y)+(a.z+a.w);
            s += __shfl_xor(s, 1, 64); s += __shfl_xor(s, 2, 64);
            if (q4 == 0 && di < NPIX) smC0[di] = inb ? s : 0.f;
        }
        __syncthreads();

        // softmax over 169 -> expected offset (wave reduce + 4-slot combine)
        const float dv = (tid < NPIX) ? smC0[tid] : 0.f;
        {
            float wm = wave_max(tid < NPIX ? dv : -INFINITY);
            if (lane == 0) rbuf[wid] = wm;
        }
        __syncthreads();
        const float M1 = fmaxf(fmaxf(rbuf[0], rbuf[1]), fmaxf(rbuf[2], rbuf[3]));
        {
            const float e   = (tid < NPIX) ? __expf(dv - M1) : 0.f;
            const float gvj = (tid < NPIX) ? (float)(tid % PPIX - RPIX) : 0.f;
            const float gvi = (tid < NPIX) ? (float)(tid / PPIX - RPIX) : 0.f;
            float s0 = wave_sum(e), s1 = wave_sum(e*gvj), s2 = wave_sum(e*gvi);
            if (lane == 0) { rbuf[4+wid] = s0; rbuf[8+wid] = s1; rbuf[12+wid] = s2; }
        }
        __syncthreads();
        const float ssum = rbuf[4]+rbuf[5]+rbuf[6]+rbuf[7];
        const float sx   = rbuf[8]+rbuf[9]+rbuf[10]+rbuf[11];
        const float sy   = rbuf[12]+rbuf[13]+rbuf[14]+rbuf[15];
        const float off_x = sx / ssum * (float)DIRATE_;
        const float off_y = sy / ssum * (float)DIRATE_;

        const float fy = (float)y + off_y, fx = (float)x + off_x;
        const float fly = floorf(fy), flx = floorf(fx);
        const int yb = (int)fly - RPIX, xb = (int)flx - RPIX;
        const float wy = fy - fly, wx = fx - flx;
        const float w00 = (1.f-wy)*(1.f-wx), w01 = (1.f-wy)*wx;
        const float w10 = wy*(1.f-wx),       w11 = wy*wx;

        // ---- 365 dots (196 G-grid on r0 + 169 corr1 on r1), 4 lanes each ----
        #pragma unroll 1
        for (int set = 0; set < 6; ++set) {
            const int di = set*64 + wid*16 + g4;
            const float4* basep = Tr0q;
            int inb = 0, yx = 0;
            if (di < NG) {
                const int ys = yb + di/G14, xs = xb + di%G14;
                inb = (ys>=0 && ys<HH && xs>=0 && xs<WW);
                yx = inb ? ys*WW+xs : 0;
            } else if (di < NG+NPIX) {
                const int k = di - NG;
                const int ys = y + k/PPIX - RPIX, xs = x + k%PPIX - RPIX;
                inb = (ys>=0 && ys<HH && xs>=0 && xs<WW);
                yx = inb ? ys*WW+xs : 0;
                basep = Tr1q;
            }
            const float4* rp = basep + yx*32 + q4;
            float4 a; a.x=a.y=a.z=a.w=0.f;
            #pragma unroll
            for (int r = 0; r < 8; ++r) {
                const float4 rv = rp[r*4];
                a.x = fmaf(rv.x,tf[r].x,a.x); a.y = fmaf(rv.y,tf[r].y,a.y);
                a.z = fmaf(rv.z,tf[r].z,a.z); a.w = fmaf(rv.w,tf[r].w,a.w);
            }
            float s = (a.x+a.y)+(a.z+a.w);
            s += __shfl_xor(s, 1, 64); s += __shfl_xor(s, 2, 64);
            if (q4 == 0 && di < NG+NPIX) {
                if (di < NG) smG[di] = inb ? s : 0.f;
                else         smC1[di-NG] = inb ? s : 0.f;
            }
        }
        // stage qr0 (14x14 grid) and qr1 (13x13), 3 ch, from compact slices
        for (int idx = tid; idx < 3*NG; idx += 256) {
            const int ch = idx / NG, a2 = idx % NG;
            const int ys = yb + a2 / G14, xs = xb + a2 % G14;
            smQ0[idx] = (ys>=0 && ys<HH && xs>=0 && xs<WW)
                        ? qs0[(b*3+ch)*1024 + ys*WW + xs] : 0.f;
        }
        for (int idx = tid; idx < 3*NPIX; idx += 256) {
            const int ch = idx / NPIX, a2 = idx % NPIX;
            const int ys = y + a2 / PPIX - RPIX, xs = x + a2 % PPIX - RPIX;
            smQ1[idx] = (ys>=0 && ys<HH && xs>=0 && xs<WW)
                        ? qs1[(b*3+ch)*1024 + ys*WW + xs] : 0.f;
        }
        __syncthreads();

        // ---- logits = concat(bilinear(G), corr1) ----
        for (int idx = tid; idx < NTOT; idx += 256) {
            float v;
            if (idx < NPIX) {
                const int i = idx / PPIX, j = idx % PPIX;
                const int g = i*G14 + j;
                v = w00*smG[g] + w01*smG[g+1] + w10*smG[g+G14] + w11*smG[g+G14+1];
            } else {
                v = smC1[idx - NPIX];
            }
            smV[idx] = v;
        }
        __syncthreads();

        // ---- fused softmax + (corr_pixel * image_uf).sum(n) ----
        float ml = -INFINITY;
        for (int idx = tid; idx < NTOT; idx += 256) ml = fmaxf(ml, smV[idx]);
        {
            float wm = wave_max(ml);
            if (lane == 0) rbuf[16+wid] = wm;
        }
        __syncthreads();
        const float M2 = fmaxf(fmaxf(rbuf[16], rbuf[17]), fmaxf(rbuf[18], rbuf[19]));

        float dpart = 0.f, o0 = 0.f, o1 = 0.f, o2 = 0.f;
        for (int idx = tid; idx < NTOT; idx += 256) {
            const float ee = __expf(smV[idx] - M2);
            dpart += ee;
            if (idx < NPIX) {
                const int i = idx / PPIX, j = idx % PPIX;
                const int g = i*G14 + j;
                o0 += ee * (w00*smQ0[g]          + w01*smQ0[g+1]
                          + w10*smQ0[g+G14]      + w11*smQ0[g+G14+1]);
                o1 += ee * (w00*smQ0[NG+g]       + w01*smQ0[NG+g+1]
                          + w10*smQ0[NG+g+G14]   + w11*smQ0[NG+g+G14+1]);
                o2 += ee * (w00*smQ0[2*NG+g]     + w01*smQ0[2*NG+g+1]
                          + w10*smQ0[2*NG+g+G14] + w11*smQ0[2*NG+g+G14+1]);
            } else {
                const int k = idx - NPIX;
                o0 += ee * smQ1[k];
                o1 += ee * smQ1[NPIX + k];
                o2 += ee * smQ1[2*NPIX + k];
            }
        }
        {
            float s0 = wave_sum(dpart), s1 = wave_sum(o0), s2 = wave_sum(o1), s3 = wave_sum(o2);
            if (lane == 0) { rbuf[20+wid]=s0; rbuf[24+wid]=s1; rbuf[28+wid]=s2; rbuf[32+wid]=s3; }
        }
        __syncthreads();
        if (tid == 0) {
            const float denom = rbuf[20]+rbuf[21]+rbuf[22]+rbuf[23];
            const float inv = 1.f / denom;
            out[((b*3+0)*HH + y)*WW + x] = (rbuf[24]+rbuf[25]+rbuf[26]+rbuf[27]) * inv;
            out[((b*3+1)*HH + y)*WW + x] = (rbuf[28]+rbuf[29]+rbuf[30]+rbuf[31]) * inv;
            out[((b*3+2)*HH + y)*WW + x] = (rbuf[32]+rbuf[33]+rbuf[34]+rbuf[35]) * inv;
        }
    } else {
        // ---- region correlation on semantic feats + softmax ----
        const int rb0 = blockIdx.x - MAIN_BLOCKS;
        const int rb  = (rb0 & 7) * (REG_BLOCKS/8) + (rb0 >> 3);  // XCD swizzle
        const int b   = rb >> 8;
        const int pix = rb & 255;
        const int y = pix >> 4, x = pix & 15;

        // stage 512-ch t-vector (contiguous)
        if (tid < 128)
            ((float4*)tvec)[tid] = ((const float4*)Tts)[(size_t)b*32768 + pix*128 + tid];
        __syncthreads();

        const float4* tp  = (const float4*)tvec;
        const float4* Tsq = (const float4*)Trs1 + (size_t)b*32768;
        const int q16 = lane & 15, g16 = lane >> 4;   // 4 dot-groups per wave

        // hoist t-fragment: 8 float4 (32 ch) per lane
        float4 tf[8];
        #pragma unroll
        for (int r = 0; r < 8; ++r) tf[r] = tp[q16 + r*16];

        // 49 dots x 512 ch, 16 lanes per dot
        #pragma unroll 1
        for (int set = 0; set < 4; ++set) {
            const int di = set*16 + wid*4 + g16;
            int inb = 0, yx = 0;
            if (di < NREG) {
                const int ys = y + di/PREG - RREG, xs = x + di%PREG - RREG;
                inb = (ys>=0 && ys<HS && xs>=0 && xs<WSz);
                yx = inb ? ys*WSz+xs : 0;
            }
            const float4* rp = Tsq + yx*128 + q16;
            float4 a; a.x=a.y=a.z=a.w=0.f;
            #pragma unroll
            for (int r = 0; r < 8; ++r) {
                const float4 rv = rp[r*16];
                a.x = fmaf(rv.x,tf[r].x,a.x); a.y = fmaf(rv.y,tf[r].y,a.y);
                a.z = fmaf(rv.z,tf[r].z,a.z); a.w = fmaf(rv.w,tf[r].w,a.w);
            }
            float s = (a.x+a.y)+(a.z+a.w);
            s += __shfl_xor(s, 1, 64); s += __shfl_xor(s, 2, 64);
            s += __shfl_xor(s, 4, 64); s += __shfl_xor(s, 8, 64);
            if (q16 == 0 && di < NREG) smG[di] = inb ? s : 0.f;
        }
        __syncthreads();

        const bool act = tid < NREG;
        const float val = act ? smG[tid] : -INFINITY;
        {
            float wm = wave_max(val);
            if (lane == 0) rbuf[wid] = wm;
        }
        __syncthreads();
        const float M = fmaxf(fmaxf(rbuf[0], rbuf[1]), fmaxf(rbuf[2], rbuf[3]));
        const float e = act ? __expf(val - M) : 0.f;
        {
            float s0 = wave_sum(e);
            if (lane == 0) rbuf[4+wid] = s0;
        }
        __syncthreads();
        const float s = rbuf[4]+rbuf[5]+rbuf[6]+rbuf[7];
        if (act) corr_out[b*NREG*(HS*WSz) + tid*(HS*WSz) + pix] = e / s;
    }
}

extern "C" void kernel_launch(void* const* d_in, const int* in_sizes, int n_in,
                              void* d_out, int out_size, void* d_ws, size_t ws_size,
                              hipStream_t stream) {
    const float* feats_r0 = (const float*)d_in[0];
    const float* feats_r1 = (const float*)d_in[1];
    const float* feats_t  = (const float*)d_in[2];
    const float* q_r0     = (const float*)d_in[3];
    const float* q_r1     = (const float*)d_in[4];
    // d_in[5] = feats_r_semantic0 (unused by reference)
    const float* rs1      = (const float*)d_in[6];
    const float* ts       = (const float*)d_in[7];

    float* ws = (float*)d_ws;
    float* Tr0  = ws;               // 2*1024*128 = 262144
    float* Tr1  = Tr0  + 262144;
    float* Tt   = Tr1  + 262144;
    float* Trs1 = Tt   + 262144;    // 2*256*512 = 262144
    float* Tts  = Trs1 + 262144;
    float* qs0  = Tts  + 262144;    // 2*3*32*32 = 6144
    float* qs1  = qs0  + 6144;

    prep<<<1288, 256, 0, stream>>>(feats_r0, feats_r1, feats_t, q_r0, q_r1,
                                   rs1, ts, Tr0, Tr1, Tt, Trs1, Tts, qs0, qs1);

    float* out  = (float*)d_out;                 // [2,3,32,32] = 6144 floats
    float* corr = out + 2*3*HH*WW;               // [2,1,49,256] = 25088 floats

    colorizer_fused<<<MAIN_BLOCKS + REG_BLOCKS, 256, 0, stream>>>(
        Tr0, Tr1, Tt, qs0, qs1, Trs1, Tts, out, corr);
}